// Round 12
// baseline (133.832 us; speedup 1.0000x reference)
//
#include <hip/hip_runtime.h>
#include <hip/hip_bf16.h>
#include <cstdint>

// N=2, L=2048, H=8, d=64, D=512. Inputs/outputs f32; features bf16 + MFMA.

typedef __bf16 bf16x8 __attribute__((ext_vector_type(8)));
typedef float f32x16 __attribute__((ext_vector_type(16)));
typedef unsigned short u16x8 __attribute__((ext_vector_type(8)));
typedef uint32_t u32x4 __attribute__((ext_vector_type(4)));

__device__ __forceinline__ unsigned short f2bfu(float f) {
    uint32_t u = __float_as_uint(f);
    uint32_t r = (u + 0x7fffu + ((u >> 16) & 1u)) >> 16;
    return (unsigned short)r;
}
__device__ __forceinline__ uint32_t cvt2(float a, float b) {
    __hip_bfloat162 h = __float22bfloat162_rn(make_float2(a, b));
    return *reinterpret_cast<uint32_t*>(&h);
}
__device__ __forceinline__ float softplusf(float x) {
    return fmaxf(x, 0.f) + __logf(1.f + __expf(-fabsf(x)));
}
__device__ __forceinline__ uint32_t pkbf(float a, float b) {
    uint32_t d;
    asm("v_cvt_pk_bf16_f32 %0, %1, %2" : "=v"(d) : "v"(a), "v"(b));
    return d;
}
__device__ __forceinline__ void plswap(uint32_t& a, uint32_t& b) {
    asm volatile("v_permlane32_swap_b32 %0, %1" : "+v"(a), "+v"(b));
}
// async global->LDS, 16B per lane; dest is wave-uniform base + lane*16
__device__ __forceinline__ void gload16(const unsigned short* g, unsigned short* l) {
    __builtin_amdgcn_global_load_lds(
        (const __attribute__((address_space(1))) unsigned int*)g,
        (__attribute__((address_space(3))) unsigned int*)l, 16, 0, 0);
}

// ---------------------------------------------------------------------------
// cvt: one-shot f32 -> bf16 of query/key/Wq/Wk/Wv. r5 version (best-known).
// ---------------------------------------------------------------------------
__global__ __launch_bounds__(256) void cvt_kernel(
    const float* __restrict__ query, const float* __restrict__ key,
    const float* __restrict__ Wq, const float* __restrict__ Wk,
    const float* __restrict__ Wv,
    unsigned short* __restrict__ Xqb, unsigned short* __restrict__ Xkb,
    unsigned short* __restrict__ Wqb, unsigned short* __restrict__ Wkb,
    unsigned short* __restrict__ Wvb)
{
    const int z = blockIdx.z;
    const float* src;
    unsigned short* dst;
    int n8;
    if (z == 0)      { src = query; dst = Xqb; n8 = 4096 * 512 / 8; }
    else if (z == 1) { src = key;   dst = Xkb; n8 = 4096 * 512 / 8; }
    else if (z == 2) { src = Wq;    dst = Wqb; n8 = 512 * 512 / 8;  }
    else if (z == 3) { src = Wk;    dst = Wkb; n8 = 512 * 512 / 8;  }
    else             { src = Wv;    dst = Wvb; n8 = 512 * 512 / 8;  }
    int idx = blockIdx.x * 256 + threadIdx.x;
    if (idx >= n8) return;
    const float4* s = (const float4*)src + (size_t)idx * 2;
    float4 a = s[0], b = s[1];
    uint4 o;
    o.x = cvt2(a.x, a.y); o.y = cvt2(a.z, a.w);
    o.z = cvt2(b.x, b.y); o.w = cvt2(b.z, b.w);
    *(uint4*)&dst[(size_t)idx * 8] = o;
}

// ---------------------------------------------------------------------------
// proj v3 (r5 version verbatim, best-known): 128x64 tiles, 768 blocks (3/CU).
// ---------------------------------------------------------------------------
__global__ __launch_bounds__(256) void proj_kernel(
    const unsigned short* __restrict__ Xqb, const unsigned short* __restrict__ Xkb,
    const unsigned short* __restrict__ Wqb, const unsigned short* __restrict__ Wkb,
    const unsigned short* __restrict__ Wvb, const float* __restrict__ coef,
    const float* __restrict__ posw, const float* __restrict__ posb,
    unsigned short* __restrict__ Af, unsigned short* __restrict__ Bf,
    unsigned short* __restrict__ Vf)
{
    const int mode = blockIdx.z;
    const int c0 = blockIdx.x * 64;    // 8 tiles
    const int m0 = blockIdx.y * 128;   // 32 tiles
    const unsigned short* X = (mode == 0) ? Xqb : Xkb;
    const unsigned short* W = (mode == 0) ? Wqb : (mode == 1 ? Wkb : Wvb);

    __shared__ __align__(16) char smem[(128 + 64) * 72 * 2];  // 27648 B
    unsigned short* Xs = (unsigned short*)smem;                   // [128][72]
    unsigned short* Ws = (unsigned short*)(smem + 128 * 72 * 2);  // [64][72]

    const int t = threadIdx.x;
    const int lane = t & 63, wv = t >> 6;
    const int lm = lane & 31, half = lane >> 5;
    const int wrow = wv >> 1, wcol = wv & 1;

    f32x16 acc[2] = {};

    u16x8 px[4], pw[2];
    {
#pragma unroll
        for (int it = 0; it < 4; ++it) {
            int cid = t + it * 256, row = cid >> 3, seg = cid & 7;
            px[it] = *(const u16x8*)&X[(size_t)(m0 + row) * 512 + seg * 8];
        }
#pragma unroll
        for (int it = 0; it < 2; ++it) {
            int cid = t + it * 256, row = cid >> 3, seg = cid & 7;
            pw[it] = *(const u16x8*)&W[(size_t)(c0 + row) * 512 + seg * 8];
        }
    }

    for (int kt = 0; kt < 8; ++kt) {
        __syncthreads();
#pragma unroll
        for (int it = 0; it < 4; ++it) {
            int cid = t + it * 256, row = cid >> 3, seg = cid & 7;
            *(u16x8*)&Xs[row * 72 + seg * 8] = px[it];
        }
#pragma unroll
        for (int it = 0; it < 2; ++it) {
            int cid = t + it * 256, row = cid >> 3, seg = cid & 7;
            *(u16x8*)&Ws[row * 72 + seg * 8] = pw[it];
        }
        __syncthreads();
        if (kt < 7) {
            int ko = (kt + 1) * 64;
#pragma unroll
            for (int it = 0; it < 4; ++it) {
                int cid = t + it * 256, row = cid >> 3, seg = cid & 7;
                px[it] = *(const u16x8*)&X[(size_t)(m0 + row) * 512 + ko + seg * 8];
            }
#pragma unroll
            for (int it = 0; it < 2; ++it) {
                int cid = t + it * 256, row = cid >> 3, seg = cid & 7;
                pw[it] = *(const u16x8*)&W[(size_t)(c0 + row) * 512 + ko + seg * 8];
            }
        }
        const unsigned short* ab = &Xs[(64 * wrow + lm) * 72 + half * 8];
        const unsigned short* bb = &Ws[(32 * wcol + lm) * 72 + half * 8];
        __builtin_amdgcn_s_setprio(1);
#pragma unroll
        for (int ks = 0; ks < 4; ++ks) {
            bf16x8 a0 = *(const bf16x8*)(ab + ks * 16);
            bf16x8 a1 = *(const bf16x8*)(ab + 32 * 72 + ks * 16);
            bf16x8 b  = *(const bf16x8*)(bb + ks * 16);
            acc[0] = __builtin_amdgcn_mfma_f32_32x32x16_bf16(a0, b, acc[0], 0, 0, 0);
            acc[1] = __builtin_amdgcn_mfma_f32_32x32x16_bf16(a1, b, acc[1], 0, 0, 0);
        }
        __builtin_amdgcn_s_setprio(0);
    }

    if (mode != 2) {
        unsigned short* Feat = (mode == 0) ? Af : Bf;
        int c = c0 + 32 * wcol + lm;
        int h = c >> 6, jj = c & 63;
        float wgt = posw[c];
        float bia = (mode == 0) ? posb[c] : 0.f;
        float cf  = (mode == 1) ? coef[c] : 1.f;
#pragma unroll
        for (int i = 0; i < 2; ++i)
#pragma unroll
        for (int r = 0; r < 16; ++r) {
            int rl = (r & 3) + 8 * (r >> 2) + 4 * half;
            int m = m0 + 64 * wrow + 32 * i + rl;
            int n = m >> 11, l = m & 2047;
            float ang = (float)l * wgt + bia;
            float sn, cs; __sincosf(ang, &sn, &cs);
            float v = softplusf(acc[i][r]) * cf;
            size_t base = ((size_t)(n * 8 + h) * 2048 + l) * 128 + jj;
            Feat[base]      = f2bfu(v * cs);
            Feat[base + 64] = f2bfu(v * sn);
        }
    } else {
        float* tb = (float*)smem;
        float* tbw = tb + wv * (32 * 34);
        __syncthreads();
#pragma unroll
        for (int i = 0; i < 2; ++i) {
#pragma unroll
            for (int r = 0; r < 16; ++r) {
                int rl = (r & 3) + 8 * (r >> 2) + 4 * half;
                tbw[lm * 34 + rl] = acc[i][r];
            }
            int mb = m0 + 64 * wrow + 32 * i;
            int n = mb >> 11, l0 = mb & 2047;
#pragma unroll
            for (int rep = 0; rep < 16; ++rep) {
                int cl = rep * 2 + half;
                float v = tbw[cl * 34 + lm];
                int c = c0 + 32 * wcol + cl;
                int h = c >> 6, dd = c & 63;
                Vf[((size_t)(n * 8 + h) * 64 + dd) * 2048 + l0 + lm] = f2bfu(v);
            }
        }
    }
}

// ---------------------------------------------------------------------------
// attn v5: r5's T12 structure with DMA-staged K/V (global_load_lds, m151) --
// removes 6 ds_write_b128/wave-tile from wave issue, frees 48 prefetch VGPRs,
// counted vmcnt(6) keeps next tile's DMA in flight under compute.
// Rule-21 both-sides swizzle (pad dropped for linear DMA dest):
//   K: [64][128] linear, slot(16B) s_phys = s_log ^ (row&15) -> 2 lanes/bank
//   V: [64][64]  linear, s_phys = s_log ^ (row&7)  -> 4-way on 4 reads/tile
// Staging source pre-swizzled (per-lane global addr), reads XOR-swizzled.
// Q-frags direct from global (r9-validated). O-merge overlays Bsm.
// ---------------------------------------------------------------------------
__global__ __launch_bounds__(256) void attn_kernel(
    const unsigned short* __restrict__ Af, const unsigned short* __restrict__ Bf,
    const unsigned short* __restrict__ Vf, float* __restrict__ out)
{
    const int bx = blockIdx.x;
    const int nh = bx & 15;
    const int p  = bx >> 4;
    const int qq = (p < 16) ? p : 47 - p;   // bx and bx+256 complementary
    const int q0 = qq * 64;

    __shared__ __align__(16) unsigned short Bsm[2 * 64 * 128];  // 32 KB dbuf K
    __shared__ __align__(16) unsigned short Vsm[2 * 64 * 64];   // 16 KB dbuf V
    __shared__ float zf[64];

    const int t = threadIdx.x;
    const int lane = t & 63, wv = t >> 6;
    const int lm = lane & 31, half = lane >> 5;
    const int qb = wv >> 1, kb = wv & 1;
    const int n = nh >> 3, h = nh & 7;

    const unsigned short* Ah = Af + (size_t)nh * 2048 * 128;
    const unsigned short* Bh = Bf + (size_t)nh * 2048 * 128;
    const unsigned short* Vh = Vf + (size_t)nh * 64 * 2048;

    // Q-fragments straight from global (B-operand rows = q)
    bf16x8 qfrag[8];
    {
        const unsigned short* qr = &Ah[(size_t)(q0 + 32 * qb + lm) * 128 + half * 8];
#pragma unroll
        for (int c = 0; c < 8; ++c) qfrag[c] = *(const bf16x8*)(qr + c * 16);
    }
    if (t < 64) zf[t] = 0.f;

    f32x16 oacc0 = {}, oacc1 = {};
    float zsum = 0.f;

    // DMA stage of tile kt into buffer b: 4 K-chunks + 2 V-chunks per thread
    // (6 VMEM instr per wave). Source pre-swizzled so linear LDS dest lands
    // in XOR-swizzled layout.
    auto stage = [&](int kt, int b) {
        const int k0 = kt * 64;
        unsigned short* bd = Bsm + b * (64 * 128);
        unsigned short* vd = Vsm + b * (64 * 64);
#pragma unroll
        for (int it = 0; it < 4; ++it) {
            int cid = t + it * 256, row = cid >> 4, sd = cid & 15;
            gload16(&Bh[(size_t)(k0 + row) * 128 + ((sd ^ (row & 15)) << 3)],
                    bd + cid * 8);
        }
#pragma unroll
        for (int it = 0; it < 2; ++it) {
            int cid = t + it * 256, row = cid >> 3, sd = cid & 7;
            gload16(&Vh[(size_t)row * 2048 + k0 + ((sd ^ (row & 7)) << 3)],
                    vd + cid * 8);
        }
    };

    stage(0, 0);
    const int krow = 32 * kb + lm;
    const int xm16 = lm & 15, xm8 = lm & 7;

    for (int kt = 0; kt <= qq; ++kt) {
        if (kt < qq) {
            stage(kt + 1, (kt + 1) & 1);   // buf^1: all waves past prev barrier
            asm volatile("s_waitcnt vmcnt(6)" ::: "memory");   // tile kt landed
        } else {
            asm volatile("s_waitcnt vmcnt(0)" ::: "memory");
        }
        __builtin_amdgcn_s_barrier();      // tile-kt DMA visible block-wide

        const unsigned short* bsrc = Bsm + (kt & 1) * (64 * 128);
        const unsigned short* vsrc = Vsm + (kt & 1) * (64 * 64);

        // S^T = K . Q^T : sacc reg r -> k_local=(r&3)+8*(r>>2)+4*half, q = lm
        f32x16 sacc = {};
        __builtin_amdgcn_s_setprio(1);
#pragma unroll
        for (int ks = 0; ks < 8; ++ks) {
            int s = (((ks * 2 + half) ^ xm16) << 3);
            bf16x8 kf = *(const bf16x8*)&bsrc[krow * 128 + s];
            sacc = __builtin_amdgcn_mfma_f32_32x32x16_bf16(kf, qfrag[ks], sacc, 0, 0, 0);
        }
        __builtin_amdgcn_s_setprio(0);

        if (kt == qq) {   // causal mask within diagonal tile
#pragma unroll
            for (int r = 0; r < 16; ++r) {
                int kl = (r & 3) + 8 * (r >> 2) + 4 * half;
                if ((32 * kb + kl) > (32 * qb + lm)) sacc[r] = 0.f;
            }
        }
#pragma unroll
        for (int r = 0; r < 16; ++r) zsum += fabsf(sacc[r]);

        union { u32x4 u; bf16x8 b; } pa0, pa1;
        {
            uint32_t A = pkbf(sacc[0], sacc[1]);
            uint32_t B = pkbf(sacc[2], sacc[3]);
            uint32_t C = pkbf(sacc[4], sacc[5]);
            uint32_t D = pkbf(sacc[6], sacc[7]);
            plswap(A, C);
            plswap(B, D);
            pa0.u = (u32x4){A, B, C, D};
            uint32_t E = pkbf(sacc[8], sacc[9]);
            uint32_t F = pkbf(sacc[10], sacc[11]);
            uint32_t G = pkbf(sacc[12], sacc[13]);
            uint32_t H = pkbf(sacc[14], sacc[15]);
            plswap(E, G);
            plswap(F, H);
            pa1.u = (u32x4){E, F, G, H};
        }

        // O_partial += P . V : B rows = dd; V slots XOR-swizzled
        int s00 = (((4 * kb + half) ^ xm8) << 3);
        int s01 = (((4 * kb + half + 2) ^ xm8) << 3);
        bf16x8 vb00 = *(const bf16x8*)&vsrc[lm * 64 + s00];
        bf16x8 vb01 = *(const bf16x8*)&vsrc[lm * 64 + s01];
        bf16x8 vb10 = *(const bf16x8*)&vsrc[(32 + lm) * 64 + s00];
        bf16x8 vb11 = *(const bf16x8*)&vsrc[(32 + lm) * 64 + s01];
        __builtin_amdgcn_s_setprio(1);
        oacc0 = __builtin_amdgcn_mfma_f32_32x32x16_bf16(pa0.b, vb00, oacc0, 0, 0, 0);
        oacc1 = __builtin_amdgcn_mfma_f32_32x32x16_bf16(pa0.b, vb10, oacc1, 0, 0, 0);
        oacc0 = __builtin_amdgcn_mfma_f32_32x32x16_bf16(pa1.b, vb01, oacc0, 0, 0, 0);
        oacc1 = __builtin_amdgcn_mfma_f32_32x32x16_bf16(pa1.b, vb11, oacc1, 0, 0, 0);
        __builtin_amdgcn_s_setprio(0);

        asm volatile("s_waitcnt lgkmcnt(0)" ::: "memory");   // reads of cur done
        __builtin_amdgcn_sched_barrier(0);                   // before next DMA WAR
        __builtin_amdgcn_s_barrier();
    }

    // z: q = 32*qb + lm is lane-local; both kb-halves contribute via atomics
    atomicAdd(&zf[32 * qb + lm], zsum);
    __syncthreads();   // zf complete; all LDS reads done -> overlay safe

    float* Os = (float*)Bsm;   // 64 x 65 f32 = 16640 B <= 32 KB
    if (kb == 0) {
#pragma unroll
        for (int r = 0; r < 16; ++r) {
            int ql = (r & 3) + 8 * (r >> 2) + 4 * half;
            Os[(32 * qb + ql) * 65 + lm]      = oacc0[r];
            Os[(32 * qb + ql) * 65 + 32 + lm] = oacc1[r];
        }
    }
    __syncthreads();
    if (kb == 1) {
#pragma unroll
        for (int r = 0; r < 16; ++r) {
            int ql = (r & 3) + 8 * (r >> 2) + 4 * half;
            int q = q0 + 32 * qb + ql;
            float invz = 1.f / zf[32 * qb + ql];
            float o0 = (Os[(32 * qb + ql) * 65 + lm]      + oacc0[r]) * invz;
            float o1 = (Os[(32 * qb + ql) * 65 + 32 + lm] + oacc1[r]) * invz;
            size_t base = ((size_t)(n * 2048 + q)) * 512 + h * 64;
            out[base + lm]      = o0;
            out[base + 32 + lm] = o1;
        }
    }
}

extern "C" void kernel_launch(void* const* d_in, const int* in_sizes, int n_in,
                              void* d_out, int out_size, void* d_ws, size_t ws_size,
                              hipStream_t stream) {
    (void)in_sizes; (void)n_in; (void)out_size; (void)ws_size;
    const float* query = (const float*)d_in[0];
    const float* key   = (const float*)d_in[1];
    const float* Wq    = (const float*)d_in[2];
    const float* Wk    = (const float*)d_in[3];
    const float* Wv    = (const float*)d_in[4];
    const float* coef  = (const float*)d_in[5];
    const float* posw  = (const float*)d_in[6];
    const float* posb  = (const float*)d_in[7];

    unsigned short* Af  = (unsigned short*)d_ws;            // 8 MiB
    unsigned short* Bf  = Af + (size_t)16 * 2048 * 128;     // 8 MiB
    unsigned short* Vf  = Bf + (size_t)16 * 2048 * 128;     // 4 MiB
    unsigned short* Xqb = Vf + (size_t)16 * 64 * 2048;      // 4 MiB
    unsigned short* Xkb = Xqb + (size_t)4096 * 512;         // 4 MiB
    unsigned short* Wqb = Xkb + (size_t)4096 * 512;         // 0.5 MiB
    unsigned short* Wkb = Wqb + (size_t)512 * 512;          // 0.5 MiB
    unsigned short* Wvb = Wkb + (size_t)512 * 512;          // 0.5 MiB

    cvt_kernel<<<dim3(1024, 1, 5), 256, 0, stream>>>(
        query, key, Wq, Wk, Wv, Xqb, Xkb, Wqb, Wkb, Wvb);
    proj_kernel<<<dim3(8, 32, 3), 256, 0, stream>>>(
        Xqb, Xkb, Wqb, Wkb, Wvb, coef, posw, posb, Af, Bf, Vf);
    attn_kernel<<<dim3(512), 256, 0, stream>>>(
        Af, Bf, Vf, (float*)d_out);
}

// Round 13
// 128.249 us; speedup vs baseline: 1.0435x; 1.0435x over previous
//
#include <hip/hip_runtime.h>
#include <hip/hip_bf16.h>
#include <cstdint>

// N=2, L=2048, H=8, d=64, D=512. Inputs/outputs f32; features bf16 + MFMA.
// FINAL (r13): restore of the session-best r5 configuration (128.3 us).
// Ledger: wins = T12 in-register softmax (-10us), proj 3-blocks/CU (-5us).
// Null/negative: split-k, occupancy x3, barrier structure x2, chain split,
// block order, DMA staging x3, XCD swizzle, traffic halving x2, cvt fusion.
// Both MFMA kernels are at a 2-phase structural floor (m233 regime); the
// harness workspace fill (~46us) is fixed cost.

typedef __bf16 bf16x8 __attribute__((ext_vector_type(8)));
typedef float f32x16 __attribute__((ext_vector_type(16)));
typedef unsigned short u16x8 __attribute__((ext_vector_type(8)));
typedef uint32_t u32x4 __attribute__((ext_vector_type(4)));

__device__ __forceinline__ unsigned short f2bfu(float f) {
    uint32_t u = __float_as_uint(f);
    uint32_t r = (u + 0x7fffu + ((u >> 16) & 1u)) >> 16;
    return (unsigned short)r;
}
__device__ __forceinline__ uint32_t cvt2(float a, float b) {
    __hip_bfloat162 h = __float22bfloat162_rn(make_float2(a, b));
    return *reinterpret_cast<uint32_t*>(&h);
}
__device__ __forceinline__ float softplusf(float x) {
    return fmaxf(x, 0.f) + __logf(1.f + __expf(-fabsf(x)));
}
// pack two f32 -> one u32 of 2 bf16 (src0 -> low half)
__device__ __forceinline__ uint32_t pkbf(float a, float b) {
    uint32_t d;
    asm("v_cvt_pk_bf16_f32 %0, %1, %2" : "=v"(d) : "v"(a), "v"(b));
    return d;
}
// v_permlane32_swap_b32: a[l>=32] <-> b[l-32]
__device__ __forceinline__ void plswap(uint32_t& a, uint32_t& b) {
    asm volatile("v_permlane32_swap_b32 %0, %1" : "+v"(a), "+v"(b));
}

// ---------------------------------------------------------------------------
// cvt: one-shot f32 -> bf16 of query/key/Wq/Wk/Wv (~5 us).
// ---------------------------------------------------------------------------
__global__ __launch_bounds__(256) void cvt_kernel(
    const float* __restrict__ query, const float* __restrict__ key,
    const float* __restrict__ Wq, const float* __restrict__ Wk,
    const float* __restrict__ Wv,
    unsigned short* __restrict__ Xqb, unsigned short* __restrict__ Xkb,
    unsigned short* __restrict__ Wqb, unsigned short* __restrict__ Wkb,
    unsigned short* __restrict__ Wvb)
{
    const int z = blockIdx.z;
    const float* src;
    unsigned short* dst;
    int n8;
    if (z == 0)      { src = query; dst = Xqb; n8 = 4096 * 512 / 8; }
    else if (z == 1) { src = key;   dst = Xkb; n8 = 4096 * 512 / 8; }
    else if (z == 2) { src = Wq;    dst = Wqb; n8 = 512 * 512 / 8;  }
    else if (z == 3) { src = Wk;    dst = Wkb; n8 = 512 * 512 / 8;  }
    else             { src = Wv;    dst = Wvb; n8 = 512 * 512 / 8;  }
    int idx = blockIdx.x * 256 + threadIdx.x;
    if (idx >= n8) return;
    const float4* s = (const float4*)src + (size_t)idx * 2;
    float4 a = s[0], b = s[1];
    uint4 o;
    o.x = cvt2(a.x, a.y); o.y = cvt2(a.z, a.w);
    o.z = cvt2(b.x, b.y); o.w = cvt2(b.z, b.w);
    *(uint4*)&dst[(size_t)idx * 8] = o;
}

// ---------------------------------------------------------------------------
// proj v3: 128x64 tiles, grid (8,32,3) = 768 blocks = 3/CU balanced.
// mode 0 -> Af[nh][l][128]; mode 1 -> Bf[nh][l][128]; mode 2 -> Vf[nh][dd][l]
// ---------------------------------------------------------------------------
__global__ __launch_bounds__(256) void proj_kernel(
    const unsigned short* __restrict__ Xqb, const unsigned short* __restrict__ Xkb,
    const unsigned short* __restrict__ Wqb, const unsigned short* __restrict__ Wkb,
    const unsigned short* __restrict__ Wvb, const float* __restrict__ coef,
    const float* __restrict__ posw, const float* __restrict__ posb,
    unsigned short* __restrict__ Af, unsigned short* __restrict__ Bf,
    unsigned short* __restrict__ Vf)
{
    const int mode = blockIdx.z;
    const int c0 = blockIdx.x * 64;    // 8 tiles
    const int m0 = blockIdx.y * 128;   // 32 tiles
    const unsigned short* X = (mode == 0) ? Xqb : Xkb;
    const unsigned short* W = (mode == 0) ? Wqb : (mode == 1 ? Wkb : Wvb);

    __shared__ __align__(16) char smem[(128 + 64) * 72 * 2];  // 27648 B
    unsigned short* Xs = (unsigned short*)smem;                   // [128][72]
    unsigned short* Ws = (unsigned short*)(smem + 128 * 72 * 2);  // [64][72]

    const int t = threadIdx.x;
    const int lane = t & 63, wv = t >> 6;
    const int lm = lane & 31, half = lane >> 5;
    const int wrow = wv >> 1, wcol = wv & 1;

    f32x16 acc[2] = {};

    u16x8 px[4], pw[2];
    {
#pragma unroll
        for (int it = 0; it < 4; ++it) {
            int cid = t + it * 256, row = cid >> 3, seg = cid & 7;
            px[it] = *(const u16x8*)&X[(size_t)(m0 + row) * 512 + seg * 8];
        }
#pragma unroll
        for (int it = 0; it < 2; ++it) {
            int cid = t + it * 256, row = cid >> 3, seg = cid & 7;
            pw[it] = *(const u16x8*)&W[(size_t)(c0 + row) * 512 + seg * 8];
        }
    }

    for (int kt = 0; kt < 8; ++kt) {
        __syncthreads();
#pragma unroll
        for (int it = 0; it < 4; ++it) {
            int cid = t + it * 256, row = cid >> 3, seg = cid & 7;
            *(u16x8*)&Xs[row * 72 + seg * 8] = px[it];
        }
#pragma unroll
        for (int it = 0; it < 2; ++it) {
            int cid = t + it * 256, row = cid >> 3, seg = cid & 7;
            *(u16x8*)&Ws[row * 72 + seg * 8] = pw[it];
        }
        __syncthreads();
        if (kt < 7) {
            int ko = (kt + 1) * 64;
#pragma unroll
            for (int it = 0; it < 4; ++it) {
                int cid = t + it * 256, row = cid >> 3, seg = cid & 7;
                px[it] = *(const u16x8*)&X[(size_t)(m0 + row) * 512 + ko + seg * 8];
            }
#pragma unroll
            for (int it = 0; it < 2; ++it) {
                int cid = t + it * 256, row = cid >> 3, seg = cid & 7;
                pw[it] = *(const u16x8*)&W[(size_t)(c0 + row) * 512 + ko + seg * 8];
            }
        }
        const unsigned short* ab = &Xs[(64 * wrow + lm) * 72 + half * 8];
        const unsigned short* bb = &Ws[(32 * wcol + lm) * 72 + half * 8];
        __builtin_amdgcn_s_setprio(1);
#pragma unroll
        for (int ks = 0; ks < 4; ++ks) {
            bf16x8 a0 = *(const bf16x8*)(ab + ks * 16);
            bf16x8 a1 = *(const bf16x8*)(ab + 32 * 72 + ks * 16);
            bf16x8 b  = *(const bf16x8*)(bb + ks * 16);
            acc[0] = __builtin_amdgcn_mfma_f32_32x32x16_bf16(a0, b, acc[0], 0, 0, 0);
            acc[1] = __builtin_amdgcn_mfma_f32_32x32x16_bf16(a1, b, acc[1], 0, 0, 0);
        }
        __builtin_amdgcn_s_setprio(0);
    }

    if (mode != 2) {
        unsigned short* Feat = (mode == 0) ? Af : Bf;
        int c = c0 + 32 * wcol + lm;
        int h = c >> 6, jj = c & 63;
        float wgt = posw[c];
        float bia = (mode == 0) ? posb[c] : 0.f;
        float cf  = (mode == 1) ? coef[c] : 1.f;
#pragma unroll
        for (int i = 0; i < 2; ++i)
#pragma unroll
        for (int r = 0; r < 16; ++r) {
            int rl = (r & 3) + 8 * (r >> 2) + 4 * half;
            int m = m0 + 64 * wrow + 32 * i + rl;
            int n = m >> 11, l = m & 2047;
            float ang = (float)l * wgt + bia;
            float sn, cs; __sincosf(ang, &sn, &cs);
            float v = softplusf(acc[i][r]) * cf;
            size_t base = ((size_t)(n * 8 + h) * 2048 + l) * 128 + jj;
            Feat[base]      = f2bfu(v * cs);
            Feat[base + 64] = f2bfu(v * sn);
        }
    } else {
        // transpose through LDS; per-wave private 32x34 f32 buffer overlays
        // smem (4 waves * 4352 B = 17408 B <= 27648 B).
        float* tb = (float*)smem;
        float* tbw = tb + wv * (32 * 34);
        __syncthreads();
#pragma unroll
        for (int i = 0; i < 2; ++i) {
#pragma unroll
            for (int r = 0; r < 16; ++r) {
                int rl = (r & 3) + 8 * (r >> 2) + 4 * half;
                tbw[lm * 34 + rl] = acc[i][r];
            }
            int mb = m0 + 64 * wrow + 32 * i;
            int n = mb >> 11, l0 = mb & 2047;
#pragma unroll
            for (int rep = 0; rep < 16; ++rep) {
                int cl = rep * 2 + half;
                float v = tbw[cl * 34 + lm];
                int c = c0 + 32 * wcol + cl;
                int h = c >> 6, dd = c & 63;
                Vf[((size_t)(n * 8 + h) * 64 + dd) * 2048 + l0 + lm] = f2bfu(v);
            }
        }
    }
}

// ---------------------------------------------------------------------------
// attn v2 (session-best): swapped QK^T (T12) -> P-row lane-local; in-register
// P->bf16 via cvt_pk + permlane32_swap (no S round-trip through LDS);
// complementary block pairing; in-kernel divide.
// ---------------------------------------------------------------------------
__global__ __launch_bounds__(256) void attn_kernel(
    const unsigned short* __restrict__ Af, const unsigned short* __restrict__ Bf,
    const unsigned short* __restrict__ Vf, float* __restrict__ out)
{
    const int bx = blockIdx.x;
    const int nh = bx & 15;
    const int p  = bx >> 4;
    const int qq = (p < 16) ? p : 47 - p;   // bx and bx+256 complementary
    const int q0 = qq * 64;

    __shared__ unsigned short Bs[64 * 136];   // K-features; Q-stage at init; O-merge overlay at end
    __shared__ unsigned short Vs[64 * 72];    // V [dd][k]
    __shared__ float zf[64];

    const int t = threadIdx.x;
    const int lane = t & 63, wv = t >> 6;
    const int lm = lane & 31, half = lane >> 5;
    const int qb = wv >> 1, kb = wv & 1;
    const int n = nh >> 3, h = nh & 7;

    const unsigned short* Ah = Af + (size_t)nh * 2048 * 128;
    const unsigned short* Bh = Bf + (size_t)nh * 2048 * 128;
    const unsigned short* Vh = Vf + (size_t)nh * 64 * 2048;

#pragma unroll
    for (int it = 0; it < 4; ++it) {
        int cid = t + it * 256, row = cid >> 4, off = (cid & 15) << 3;
        *(u16x8*)&Bs[row * 136 + off] = *(const u16x8*)&Ah[(size_t)(q0 + row) * 128 + off];
    }
    if (t < 64) zf[t] = 0.f;
    __syncthreads();
    bf16x8 qfrag[8];
    {
        const unsigned short* ab = &Bs[(32 * qb + lm) * 136 + half * 8];
#pragma unroll
        for (int c = 0; c < 8; ++c) qfrag[c] = *(const bf16x8*)(ab + c * 16);
    }

    f32x16 oacc0 = {}, oacc1 = {};
    float zsum = 0.f;

    u16x8 pb[4], pv[2];
#pragma unroll
    for (int it = 0; it < 4; ++it) {
        int cid = t + it * 256, row = cid >> 4, off = (cid & 15) << 3;
        pb[it] = *(const u16x8*)&Bh[(size_t)row * 128 + off];
    }
#pragma unroll
    for (int it = 0; it < 2; ++it) {
        int cid = t + it * 256, row = cid >> 3, off = (cid & 7) << 3;
        pv[it] = *(const u16x8*)&Vh[(size_t)row * 2048 + off];
    }

    for (int kt = 0; kt <= qq; ++kt) {
        __syncthreads();
#pragma unroll
        for (int it = 0; it < 4; ++it) {
            int cid = t + it * 256, row = cid >> 4, off = (cid & 15) << 3;
            *(u16x8*)&Bs[row * 136 + off] = pb[it];
        }
#pragma unroll
        for (int it = 0; it < 2; ++it) {
            int cid = t + it * 256, row = cid >> 3, off = (cid & 7) << 3;
            *(u16x8*)&Vs[row * 72 + off] = pv[it];
        }
        __syncthreads();
        if (kt < qq) {
            int k1 = (kt + 1) * 64;
#pragma unroll
            for (int it = 0; it < 4; ++it) {
                int cid = t + it * 256, row = cid >> 4, off = (cid & 15) << 3;
                pb[it] = *(const u16x8*)&Bh[(size_t)(k1 + row) * 128 + off];
            }
#pragma unroll
            for (int it = 0; it < 2; ++it) {
                int cid = t + it * 256, row = cid >> 3, off = (cid & 7) << 3;
                pv[it] = *(const u16x8*)&Vh[(size_t)row * 2048 + k1 + off];
            }
        }

        f32x16 sacc = {};
        const unsigned short* kbase = &Bs[(32 * kb + lm) * 136 + half * 8];
        __builtin_amdgcn_s_setprio(1);
#pragma unroll
        for (int ks = 0; ks < 8; ++ks) {
            bf16x8 kf = *(const bf16x8*)(kbase + ks * 16);
            sacc = __builtin_amdgcn_mfma_f32_32x32x16_bf16(kf, qfrag[ks], sacc, 0, 0, 0);
        }
        __builtin_amdgcn_s_setprio(0);

        if (kt == qq) {
#pragma unroll
            for (int r = 0; r < 16; ++r) {
                int kl = (r & 3) + 8 * (r >> 2) + 4 * half;
                if ((32 * kb + kl) > (32 * qb + lm)) sacc[r] = 0.f;
            }
        }
#pragma unroll
        for (int r = 0; r < 16; ++r) zsum += fabsf(sacc[r]);

        union { u32x4 u; bf16x8 b; } pa0, pa1;
        {
            uint32_t A = pkbf(sacc[0], sacc[1]);
            uint32_t B = pkbf(sacc[2], sacc[3]);
            uint32_t C = pkbf(sacc[4], sacc[5]);
            uint32_t D = pkbf(sacc[6], sacc[7]);
            plswap(A, C);
            plswap(B, D);
            pa0.u = (u32x4){A, B, C, D};
            uint32_t E = pkbf(sacc[8], sacc[9]);
            uint32_t F = pkbf(sacc[10], sacc[11]);
            uint32_t G = pkbf(sacc[12], sacc[13]);
            uint32_t H = pkbf(sacc[14], sacc[15]);
            plswap(E, G);
            plswap(F, H);
            pa1.u = (u32x4){E, F, G, H};
        }

        const unsigned short* v0 = &Vs[(size_t)lm * 72 + 32 * kb + half * 8];
        const unsigned short* v1 = &Vs[(size_t)(32 + lm) * 72 + 32 * kb + half * 8];
        __builtin_amdgcn_s_setprio(1);
        {
            bf16x8 vb00 = *(const bf16x8*)(v0);
            bf16x8 vb10 = *(const bf16x8*)(v1);
            oacc0 = __builtin_amdgcn_mfma_f32_32x32x16_bf16(pa0.b, vb00, oacc0, 0, 0, 0);
            oacc1 = __builtin_amdgcn_mfma_f32_32x32x16_bf16(pa0.b, vb10, oacc1, 0, 0, 0);
            bf16x8 vb01 = *(const bf16x8*)(v0 + 16);
            bf16x8 vb11 = *(const bf16x8*)(v1 + 16);
            oacc0 = __builtin_amdgcn_mfma_f32_32x32x16_bf16(pa1.b, vb01, oacc0, 0, 0, 0);
            oacc1 = __builtin_amdgcn_mfma_f32_32x32x16_bf16(pa1.b, vb11, oacc1, 0, 0, 0);
        }
        __builtin_amdgcn_s_setprio(0);
    }

    atomicAdd(&zf[32 * qb + lm], zsum);
    __syncthreads();

    float* Os = (float*)Bs;
    if (kb == 0) {
#pragma unroll
        for (int r = 0; r < 16; ++r) {
            int ql = (r & 3) + 8 * (r >> 2) + 4 * half;
            Os[(32 * qb + ql) * 65 + lm]      = oacc0[r];
            Os[(32 * qb + ql) * 65 + 32 + lm] = oacc1[r];
        }
    }
    __syncthreads();
    if (kb == 1) {
#pragma unroll
        for (int r = 0; r < 16; ++r) {
            int ql = (r & 3) + 8 * (r >> 2) + 4 * half;
            int q = q0 + 32 * qb + ql;
            float invz = 1.f / zf[32 * qb + ql];
            float o0 = (Os[(32 * qb + ql) * 65 + lm]      + oacc0[r]) * invz;
            float o1 = (Os[(32 * qb + ql) * 65 + 32 + lm] + oacc1[r]) * invz;
            size_t base = ((size_t)(n * 2048 + q)) * 512 + h * 64;
            out[base + lm]      = o0;
            out[base + 32 + lm] = o1;
        }
    }
}

extern "C" void kernel_launch(void* const* d_in, const int* in_sizes, int n_in,
                              void* d_out, int out_size, void* d_ws, size_t ws_size,
                              hipStream_t stream) {
    (void)in_sizes; (void)n_in; (void)out_size; (void)ws_size;
    const float* query = (const float*)d_in[0];
    const float* key   = (const float*)d_in[1];
    const float* Wq    = (const float*)d_in[2];
    const float* Wk    = (const float*)d_in[3];
    const float* Wv    = (const float*)d_in[4];
    const float* coef  = (const float*)d_in[5];
    const float* posw  = (const float*)d_in[6];
    const float* posb  = (const float*)d_in[7];

    unsigned short* Af  = (unsigned short*)d_ws;            // 8 MiB
    unsigned short* Bf  = Af + (size_t)16 * 2048 * 128;     // 8 MiB
    unsigned short* Vf  = Bf + (size_t)16 * 2048 * 128;     // 4 MiB
    unsigned short* Xqb = Vf + (size_t)16 * 64 * 2048;      // 4 MiB
    unsigned short* Xkb = Xqb + (size_t)4096 * 512;         // 4 MiB
    unsigned short* Wqb = Xkb + (size_t)4096 * 512;         // 0.5 MiB
    unsigned short* Wkb = Wqb + (size_t)512 * 512;          // 0.5 MiB
    unsigned short* Wvb = Wkb + (size_t)512 * 512;          // 0.5 MiB

    cvt_kernel<<<dim3(1024, 1, 5), 256, 0, stream>>>(
        query, key, Wq, Wk, Wv, Xqb, Xkb, Wqb, Wkb, Wvb);
    proj_kernel<<<dim3(8, 32, 3), 256, 0, stream>>>(
        Xqb, Xkb, Wqb, Wkb, Wvb, coef, posw, posb, Af, Bf, Vf);
    attn_kernel<<<dim3(512), 256, 0, stream>>>(
        Af, Bf, Vf, (float*)d_out);
}